// Round 2
// baseline (1472.439 us; speedup 1.0000x reference)
//
#include <hip/hip_runtime.h>
#include <hip/hip_bf16.h>

typedef __bf16 bf16;
typedef __bf16 bf16x4 __attribute__((ext_vector_type(4)));
typedef __bf16 bf16x8 __attribute__((ext_vector_type(8)));
typedef float f32x4 __attribute__((ext_vector_type(4)));

#define T_TOK 4096
#define DDIM 1024
#define FDIM 4096
#define NEXP 8

// ---------------- cast fp32 -> bf16 (x) -----------------------------------
__global__ __launch_bounds__(256) void k_cast(
    const float* __restrict__ in, bf16* __restrict__ out, int n4)
{
    int i = blockIdx.x * 256 + threadIdx.x;
    if (i >= n4) return;
    float4 v = ((const float4*)in)[i];
    bf16x4 o;
    o[0] = (bf16)v.x; o[1] = (bf16)v.y; o[2] = (bf16)v.z; o[3] = (bf16)v.w;
    ((bf16x4*)out)[i] = o;
}

// ---------------- router: fp32 logits, softmax top-2, counts, rl ----------
__global__ __launch_bounds__(256) void k_router(
    const float* __restrict__ x, const float* __restrict__ gw,
    float* __restrict__ out_rl, int* __restrict__ topE, float* __restrict__ topW,
    int* __restrict__ cnt)
{
    int wid = threadIdx.x >> 6, lane = threadIdx.x & 63;
    int t = blockIdx.x * 4 + wid;   // 1024 blocks x 4 waves
    const float4* xr = (const float4*)(x + (size_t)t * DDIM);
    const float4* gr = (const float4*)gw;
    float acc[NEXP];
#pragma unroll
    for (int e = 0; e < NEXP; ++e) acc[e] = 0.f;
#pragma unroll
    for (int i = 0; i < 4; ++i) {
        float4 xv = xr[lane + 64 * i];
#pragma unroll
        for (int e = 0; e < NEXP; ++e) {
            float4 gv = gr[e * 256 + lane + 64 * i];
            acc[e] += xv.x * gv.x + xv.y * gv.y + xv.z * gv.z + xv.w * gv.w;
        }
    }
#pragma unroll
    for (int e = 0; e < NEXP; ++e) {
#pragma unroll
        for (int s = 32; s > 0; s >>= 1) acc[e] += __shfl_down(acc[e], s, 64);
    }
    if (lane == 0) {
        float mx = acc[0];
#pragma unroll
        for (int e = 1; e < NEXP; ++e) mx = fmaxf(mx, acc[e]);
        float p[NEXP];
#pragma unroll
        for (int e = 0; e < NEXP; ++e) p[e] = __expf(acc[e] - mx);
        int e0 = 0;
#pragma unroll
        for (int e = 1; e < NEXP; ++e) if (p[e] > p[e0]) e0 = e;
        int e1 = (e0 == 0) ? 1 : 0;
#pragma unroll
        for (int e = 0; e < NEXP; ++e) if (e != e0 && p[e] > p[e1]) e1 = e;
        float s = p[e0] + p[e1];
        topE[2 * t] = e0; topE[2 * t + 1] = e1;
        topW[2 * t] = p[e0] / s; topW[2 * t + 1] = p[e1] / s;
        atomicAdd(&cnt[e0], 1); atomicAdd(&cnt[e1], 1);
        int b = t >> 10;
#pragma unroll
        for (int e = 0; e < NEXP; ++e)
            atomicAdd(&out_rl[b * NEXP + e], acc[e] * (1.f / 1024.f));
    }
}

// ---------------- tiny exclusive scan over 8 experts ----------------------
__global__ void k_scan(const int* __restrict__ cnt, int* __restrict__ offs,
                       int* __restrict__ fill)
{
    if (threadIdx.x == 0) {
        int s = 0;
        for (int e = 0; e < NEXP; ++e) { offs[e] = s; s += cnt[e]; }
    }
    if (threadIdx.x < NEXP) fill[threadIdx.x] = 0;
}

// ---------------- build per-expert token lists ----------------------------
__global__ __launch_bounds__(256) void k_build(
    const int* __restrict__ topE, const float* __restrict__ topW,
    const int* __restrict__ offs, int* __restrict__ fill,
    int* __restrict__ list, float* __restrict__ wlist)
{
    int t = blockIdx.x * blockDim.x + threadIdx.x;
    if (t >= T_TOK) return;
#pragma unroll
    for (int k = 0; k < 2; ++k) {
        int e = topE[2 * t + k];
        int p = atomicAdd(&fill[e], 1);
        int s = offs[e] + p;
        list[s] = t;
        wlist[s] = topW[2 * t + k];
    }
}

// ------ weight transpose+cast [E][R][C] fp32 -> [E][C][R] bf16 ------------
__global__ __launch_bounds__(256) void k_tc(
    const float* __restrict__ in, bf16* __restrict__ out, int R, int C)
{
    __shared__ float tile[32][33];
    int e = blockIdx.z;
    const float* I = in + (size_t)e * R * C;
    bf16* O = out + (size_t)e * R * C;
    int c0 = blockIdx.x * 32, r0 = blockIdx.y * 32;
    int tx = threadIdx.x, ty = threadIdx.y;  // 32 x 8
#pragma unroll
    for (int k = 0; k < 32; k += 8)
        tile[ty + k][tx] = I[(size_t)(r0 + ty + k) * C + c0 + tx];
    __syncthreads();
#pragma unroll
    for (int k = 0; k < 32; k += 8)
        O[(size_t)(c0 + ty + k) * R + r0 + tx] = (bf16)tile[tx][ty + k];
}

// ------ fused GEMM: H = silu(Xg@w1t) * (Xg@w3t) * w_slot, 128x128x32 ------
__global__ __launch_bounds__(256) void k_gemm01(
    const bf16* __restrict__ xb, const bf16* __restrict__ B1w,
    const bf16* __restrict__ B3w, bf16* __restrict__ Hbuf,
    const int* __restrict__ cnt, const int* __restrict__ offs,
    const int* __restrict__ list, const float* __restrict__ wlist)
{
    const int e = blockIdx.z, mt = blockIdx.y, nt = blockIdx.x;
    const int count = cnt[e];
    if (mt * 128 >= count) return;
    const int off = offs[e];
    const int tid = threadIdx.x;
    const int lane = tid & 63;
    const int wid = tid >> 6;
    const int wm = (wid >> 1) * 64, wn = (wid & 1) * 64;
    const int lr = lane & 15, lk = (lane >> 4) * 8;

    __shared__ __attribute__((aligned(16))) bf16 As[128 * 32];
    __shared__ __attribute__((aligned(16))) bf16 B1s[128 * 32];
    __shared__ __attribute__((aligned(16))) bf16 B3s[128 * 32];
    __shared__ int tokbuf[128];

    if (tid < 128) {
        int p = mt * 128 + tid;
        tokbuf[tid] = (p < count) ? list[off + p] : -1;
    }
    __syncthreads();

    f32x4 acc1[4][4], acc3[4][4];
#pragma unroll
    for (int i = 0; i < 4; ++i)
#pragma unroll
        for (int j = 0; j < 4; ++j)
#pragma unroll
            for (int r = 0; r < 4; ++r) { acc1[i][j][r] = 0.f; acc3[i][j][r] = 0.f; }

    const bf16* B1base = B1w + ((size_t)e * FDIM + (size_t)nt * 128) * DDIM;
    const bf16* B3base = B3w + ((size_t)e * FDIM + (size_t)nt * 128) * DDIM;
    const int arow = tid >> 2, aseg = tid & 3;

    for (int kk = 0; kk < DDIM; kk += 32) {
#pragma unroll
        for (int it = 0; it < 2; ++it) {
            int row = arow + it * 64;
            int col = kk + aseg * 8;
            int t = tokbuf[row];
            bf16x8 av;
            if (t >= 0) {
                av = *(const bf16x8*)(xb + (size_t)t * DDIM + col);
            } else {
#pragma unroll
                for (int z = 0; z < 8; ++z) av[z] = (bf16)0.f;
            }
            *(bf16x8*)(As + row * 32 + aseg * 8) = av;
            *(bf16x8*)(B1s + row * 32 + aseg * 8) =
                *(const bf16x8*)(B1base + (size_t)row * DDIM + col);
            *(bf16x8*)(B3s + row * 32 + aseg * 8) =
                *(const bf16x8*)(B3base + (size_t)row * DDIM + col);
        }
        __syncthreads();
        bf16x8 af[4], b1f[4], b3f[4];
#pragma unroll
        for (int i = 0; i < 4; ++i)
            af[i] = *(const bf16x8*)(As + (wm + i * 16 + lr) * 32 + lk);
#pragma unroll
        for (int j = 0; j < 4; ++j) {
            b1f[j] = *(const bf16x8*)(B1s + (wn + j * 16 + lr) * 32 + lk);
            b3f[j] = *(const bf16x8*)(B3s + (wn + j * 16 + lr) * 32 + lk);
        }
#pragma unroll
        for (int i = 0; i < 4; ++i)
#pragma unroll
            for (int j = 0; j < 4; ++j) {
                acc1[i][j] = __builtin_amdgcn_mfma_f32_16x16x32_bf16(
                    af[i], b1f[j], acc1[i][j], 0, 0, 0);
                acc3[i][j] = __builtin_amdgcn_mfma_f32_16x16x32_bf16(
                    af[i], b3f[j], acc3[i][j], 0, 0, 0);
            }
        __syncthreads();
    }

    // C/D layout: col = lane&15, row = (lane>>4)*4 + reg
    const int lcol = lane & 15, lrow0 = (lane >> 4) * 4;
#pragma unroll
    for (int i = 0; i < 4; ++i) {
#pragma unroll
        for (int r = 0; r < 4; ++r) {
            int p = mt * 128 + wm + i * 16 + lrow0 + r;
            if (p >= count) continue;
            int slot = off + p;
            float wl = wlist[slot];
#pragma unroll
            for (int j = 0; j < 4; ++j) {
                int n = nt * 128 + wn + j * 16 + lcol;
                float a = acc1[i][j][r];
                float sv = a / (1.f + __expf(-a));
                Hbuf[(size_t)slot * FDIM + n] = (bf16)(sv * acc3[i][j][r] * wl);
            }
        }
    }
}

// ------ GEMM2: out[tok] += H @ w2t, scatter via fp32 atomics --------------
__global__ __launch_bounds__(256) void k_gemm2(
    const bf16* __restrict__ Hbuf, const bf16* __restrict__ B2w,
    float* __restrict__ out,
    const int* __restrict__ cnt, const int* __restrict__ offs,
    const int* __restrict__ list)
{
    const int e = blockIdx.z, mt = blockIdx.y, nt = blockIdx.x;
    const int count = cnt[e];
    if (mt * 128 >= count) return;
    const int off = offs[e];
    const int tid = threadIdx.x;
    const int lane = tid & 63;
    const int wid = tid >> 6;
    const int wm = (wid >> 1) * 64, wn = (wid & 1) * 64;
    const int lr = lane & 15, lk = (lane >> 4) * 8;

    __shared__ __attribute__((aligned(16))) bf16 As[128 * 32];
    __shared__ __attribute__((aligned(16))) bf16 Bs[128 * 32];

    f32x4 acc[4][4];
#pragma unroll
    for (int i = 0; i < 4; ++i)
#pragma unroll
        for (int j = 0; j < 4; ++j)
#pragma unroll
            for (int r = 0; r < 4; ++r) acc[i][j][r] = 0.f;

    const bf16* Bbase = B2w + ((size_t)e * DDIM + (size_t)nt * 128) * FDIM;
    const int arow = tid >> 2, aseg = tid & 3;

    for (int kk = 0; kk < FDIM; kk += 32) {
#pragma unroll
        for (int it = 0; it < 2; ++it) {
            int row = arow + it * 64;
            int col = kk + aseg * 8;
            int p = mt * 128 + row;
            bool valid = (p < count);
            bf16x8 av;
            if (valid) {
                av = *(const bf16x8*)(Hbuf + (size_t)(off + p) * FDIM + col);
            } else {
#pragma unroll
                for (int z = 0; z < 8; ++z) av[z] = (bf16)0.f;
            }
            *(bf16x8*)(As + row * 32 + aseg * 8) = av;
            *(bf16x8*)(Bs + row * 32 + aseg * 8) =
                *(const bf16x8*)(Bbase + (size_t)row * FDIM + col);
        }
        __syncthreads();
        bf16x8 af[4], bfr[4];
#pragma unroll
        for (int i = 0; i < 4; ++i)
            af[i] = *(const bf16x8*)(As + (wm + i * 16 + lr) * 32 + lk);
#pragma unroll
        for (int j = 0; j < 4; ++j)
            bfr[j] = *(const bf16x8*)(Bs + (wn + j * 16 + lr) * 32 + lk);
#pragma unroll
        for (int i = 0; i < 4; ++i)
#pragma unroll
            for (int j = 0; j < 4; ++j)
                acc[i][j] = __builtin_amdgcn_mfma_f32_16x16x32_bf16(
                    af[i], bfr[j], acc[i][j], 0, 0, 0);
        __syncthreads();
    }

    const int lcol = lane & 15, lrow0 = (lane >> 4) * 4;
#pragma unroll
    for (int i = 0; i < 4; ++i) {
#pragma unroll
        for (int r = 0; r < 4; ++r) {
            int p = mt * 128 + wm + i * 16 + lrow0 + r;
            if (p >= count) continue;
            int t = list[off + p];
#pragma unroll
            for (int j = 0; j < 4; ++j) {
                int n = nt * 128 + wn + j * 16 + lcol;
                atomicAdd(&out[(size_t)t * DDIM + n], acc[i][j][r]);
            }
        }
    }
}

extern "C" void kernel_launch(void* const* d_in, const int* in_sizes, int n_in,
                              void* d_out, int out_size, void* d_ws, size_t ws_size,
                              hipStream_t stream)
{
    const float* x  = (const float*)d_in[0];
    const float* gw = (const float*)d_in[1];
    const float* w1 = (const float*)d_in[2];
    const float* w3 = (const float*)d_in[3];
    const float* w2 = (const float*)d_in[4];
    float* out = (float*)d_out;

    char* ws = (char*)d_ws;
    size_t o = 0;
    auto alloc = [&](size_t bytes) {
        char* p = ws + o;
        o += (bytes + 255) & ~(size_t)255;
        return p;
    };
    const size_t wsz = (size_t)NEXP * DDIM * FDIM * sizeof(bf16);   // 64 MiB
    bf16*  w1t   = (bf16*)alloc(wsz);          // also reused for w2t
    bf16*  w3t   = (bf16*)alloc(wsz);
    bf16*  Hbuf  = (bf16*)alloc((size_t)(2 * T_TOK) * FDIM * sizeof(bf16));
    bf16*  xb    = (bf16*)alloc((size_t)T_TOK * DDIM * sizeof(bf16));
    int*   topE  = (int*)alloc(T_TOK * 2 * sizeof(int));
    float* topW  = (float*)alloc(T_TOK * 2 * sizeof(float));
    int*   cnt   = (int*)alloc(NEXP * sizeof(int));
    int*   offs  = (int*)alloc(NEXP * sizeof(int));
    int*   fill  = (int*)alloc(NEXP * sizeof(int));
    int*   list  = (int*)alloc(2 * T_TOK * sizeof(int));
    float* wlist = (float*)alloc(2 * T_TOK * sizeof(float));
    bf16*  w2t   = w1t;

    // zero output ourselves: harness poisons d_out before every timed launch
    hipMemsetAsync(out, 0, (size_t)out_size * sizeof(float), stream);
    hipMemsetAsync(cnt, 0, NEXP * sizeof(int), stream);

    float* out_rl = out + (size_t)T_TOK * DDIM;

    k_cast<<<T_TOK * DDIM / 4 / 256, 256, 0, stream>>>(x, xb, T_TOK * DDIM / 4);
    k_router<<<T_TOK / 4, 256, 0, stream>>>(x, gw, out_rl, topE, topW, cnt);
    k_scan<<<1, 64, 0, stream>>>(cnt, offs, fill);
    k_build<<<(T_TOK + 255) / 256, 256, 0, stream>>>(topE, topW, offs, fill, list, wlist);

    k_tc<<<dim3(FDIM / 32, DDIM / 32, NEXP), dim3(32, 8), 0, stream>>>(w1, w1t, DDIM, FDIM);
    k_tc<<<dim3(FDIM / 32, DDIM / 32, NEXP), dim3(32, 8), 0, stream>>>(w3, w3t, DDIM, FDIM);

    k_gemm01<<<dim3(FDIM / 128, T_TOK / 128, NEXP), 256, 0, stream>>>(
        xb, w1t, w3t, Hbuf, cnt, offs, list, wlist);

    k_tc<<<dim3(DDIM / 32, FDIM / 32, NEXP), dim3(32, 8), 0, stream>>>(w2, w2t, FDIM, DDIM);

    k_gemm2<<<dim3(DDIM / 128, T_TOK / 128, NEXP), 256, 0, stream>>>(
        Hbuf, w2t, out, cnt, offs, list);
}

// Round 3
// 1296.799 us; speedup vs baseline: 1.1354x; 1.1354x over previous
//
#include <hip/hip_runtime.h>
#include <hip/hip_bf16.h>

typedef __bf16 bf16;
typedef __bf16 bf16x4 __attribute__((ext_vector_type(4)));
typedef __bf16 bf16x8 __attribute__((ext_vector_type(8)));
typedef float f32x4 __attribute__((ext_vector_type(4)));

#define T_TOK 4096
#define DDIM 1024
#define FDIM 4096
#define NEXP 8
#define NSLOT (2 * T_TOK)          // 8192 expert-slots
#define HROWS (NSLOT + 128)        // slack for tail-tile overreads

// async global->LDS, 16B per lane; LDS dest must be wave-uniform base,
// data lands at base + lane*16 (m97/m104 semantics)
__device__ __forceinline__ void async_copy16(const void* g, void* l) {
    __builtin_amdgcn_global_load_lds(
        (const __attribute__((address_space(1))) void*)g,
        (__attribute__((address_space(3))) void*)l, 16, 0, 0);
}

// ---------------- cast fp32 -> bf16 (x) -----------------------------------
__global__ __launch_bounds__(256) void k_cast(
    const float* __restrict__ in, bf16* __restrict__ out, int n4)
{
    int i = blockIdx.x * 256 + threadIdx.x;
    if (i >= n4) return;
    float4 v = ((const float4*)in)[i];
    bf16x4 o;
    o[0] = (bf16)v.x; o[1] = (bf16)v.y; o[2] = (bf16)v.z; o[3] = (bf16)v.w;
    ((bf16x4*)out)[i] = o;
}

// ---------------- router: fp32 logits, softmax top-2, counts, rl ----------
__global__ __launch_bounds__(256) void k_router(
    const float* __restrict__ x, const float* __restrict__ gw,
    float* __restrict__ out_rl, int* __restrict__ topE, float* __restrict__ topW,
    int* __restrict__ cnt)
{
    int wid = threadIdx.x >> 6, lane = threadIdx.x & 63;
    int t = blockIdx.x * 4 + wid;
    const float4* xr = (const float4*)(x + (size_t)t * DDIM);
    const float4* gr = (const float4*)gw;
    float acc[NEXP];
#pragma unroll
    for (int e = 0; e < NEXP; ++e) acc[e] = 0.f;
#pragma unroll
    for (int i = 0; i < 4; ++i) {
        float4 xv = xr[lane + 64 * i];
#pragma unroll
        for (int e = 0; e < NEXP; ++e) {
            float4 gv = gr[e * 256 + lane + 64 * i];
            acc[e] += xv.x * gv.x + xv.y * gv.y + xv.z * gv.z + xv.w * gv.w;
        }
    }
#pragma unroll
    for (int e = 0; e < NEXP; ++e) {
#pragma unroll
        for (int s = 32; s > 0; s >>= 1) acc[e] += __shfl_down(acc[e], s, 64);
    }
    if (lane == 0) {
        float mx = acc[0];
#pragma unroll
        for (int e = 1; e < NEXP; ++e) mx = fmaxf(mx, acc[e]);
        float p[NEXP];
#pragma unroll
        for (int e = 0; e < NEXP; ++e) p[e] = __expf(acc[e] - mx);
        int e0 = 0;
#pragma unroll
        for (int e = 1; e < NEXP; ++e) if (p[e] > p[e0]) e0 = e;
        int e1 = (e0 == 0) ? 1 : 0;
#pragma unroll
        for (int e = 0; e < NEXP; ++e) if (e != e0 && p[e] > p[e1]) e1 = e;
        float s = p[e0] + p[e1];
        topE[2 * t] = e0; topE[2 * t + 1] = e1;
        topW[2 * t] = p[e0] / s; topW[2 * t + 1] = p[e1] / s;
        atomicAdd(&cnt[e0], 1); atomicAdd(&cnt[e1], 1);
        int b = t >> 10;
#pragma unroll
        for (int e = 0; e < NEXP; ++e)
            atomicAdd(&out_rl[b * NEXP + e], acc[e] * (1.f / 1024.f));
    }
}

// ---------------- tiny exclusive scan over 8 experts ----------------------
__global__ void k_scan(const int* __restrict__ cnt, int* __restrict__ offs,
                       int* __restrict__ fill)
{
    if (threadIdx.x == 0) {
        int s = 0;
        for (int e = 0; e < NEXP; ++e) { offs[e] = s; s += cnt[e]; }
    }
    if (threadIdx.x < NEXP) fill[threadIdx.x] = 0;
}

// ---------------- build per-expert token lists + inverse ------------------
__global__ __launch_bounds__(256) void k_build(
    const int* __restrict__ topE, const float* __restrict__ topW,
    const int* __restrict__ offs, int* __restrict__ fill,
    int* __restrict__ list, float* __restrict__ wlist, int* __restrict__ inv)
{
    int t = blockIdx.x * blockDim.x + threadIdx.x;
    if (t >= T_TOK) return;
#pragma unroll
    for (int k = 0; k < 2; ++k) {
        int e = topE[2 * t + k];
        int p = atomicAdd(&fill[e], 1);
        int s = offs[e] + p;
        list[s] = t;
        wlist[s] = topW[2 * t + k];
        inv[2 * t + k] = s;
    }
}

// ------ weight transpose+cast [E][R][C] fp32 -> [E][C][R] bf16, 64x64 -----
__global__ __launch_bounds__(256) void k_tc64(
    const float* __restrict__ in, bf16* __restrict__ out, int R, int C)
{
    __shared__ float tile[64][72];
    int e = blockIdx.z;
    const float* I = in + (size_t)e * R * C;
    bf16* O = out + (size_t)e * R * C;
    int c0 = blockIdx.x * 64, r0 = blockIdx.y * 64;
    int tid = threadIdx.x;
#pragma unroll
    for (int it = 0; it < 4; ++it) {
        int idx = it * 256 + tid;              // 1024 float4 slots
        int row = idx >> 4, c4 = idx & 15;
        float4 v = *(const float4*)(I + (size_t)(r0 + row) * C + c0 + c4 * 4);
        tile[row][c4 * 4 + 0] = v.x; tile[row][c4 * 4 + 1] = v.y;
        tile[row][c4 * 4 + 2] = v.z; tile[row][c4 * 4 + 3] = v.w;
    }
    __syncthreads();
#pragma unroll
    for (int it = 0; it < 4; ++it) {
        int idx = it * 256 + tid;
        int c = idx >> 4, r4 = idx & 15;
        bf16x4 o;
#pragma unroll
        for (int j = 0; j < 4; ++j) o[j] = (bf16)tile[r4 * 4 + j][c];
        *(bf16x4*)(O + (size_t)(c0 + c) * R + r0 + r4 * 4) = o;
    }
}

// ------ fused GEMM1: H = silu(Xg@w1t) * (Xg@w3t) * w_slot -----------------
// 128x128x32 tile, async staging, XOR-swizzled LDS (seg ^= (row>>1)&3)
__global__ __launch_bounds__(256) void k_gemm01(
    const bf16* __restrict__ xb, const bf16* __restrict__ B1w,
    const bf16* __restrict__ B3w, bf16* __restrict__ Hbuf,
    const int* __restrict__ cnt, const int* __restrict__ offs,
    const int* __restrict__ list, const float* __restrict__ wlist)
{
    const int e = blockIdx.z, mt = blockIdx.y, nt = blockIdx.x;
    const int count = cnt[e];
    if (mt * 128 >= count) return;
    const int off = offs[e];
    const int tid = threadIdx.x;
    const int lane = tid & 63;
    const int wid = tid >> 6;
    const int wm = (wid >> 1) * 64, wn = (wid & 1) * 64;
    const int lr = lane & 15, segn = lane >> 4;

    __shared__ __attribute__((aligned(16))) bf16 As[128 * 32];
    __shared__ __attribute__((aligned(16))) bf16 B1s[128 * 32];
    __shared__ __attribute__((aligned(16))) bf16 B3s[128 * 32];
    __shared__ int tokbuf[128];

    if (tid < 128) {
        int p = mt * 128 + tid;
        int t = (p < count) ? list[off + p] : 0;   // clamp: garbage rows skipped in epilogue
        tokbuf[tid] = t;
    }
    __syncthreads();

    // staging geometry: lane data lands at LDS elems (it*2048 + tid*8)
    const int srow = tid >> 2;                      // + it*64
    const int gseg = (tid & 3) ^ ((srow >> 1) & 3); // same for it=0/1 (row+64 keeps (row>>1)&3)
    const int ldsw = wid * 512;                     // wave-uniform base (elems), + it*2048
    const size_t acol = (size_t)gseg * 8;

    // fragment LDS offsets (constant across k-steps)
    int aoff[4], boff[4];
#pragma unroll
    for (int i = 0; i < 4; ++i) {
        int ra = wm + i * 16 + lr;
        aoff[i] = ra * 32 + ((((ra >> 1) & 3) ^ segn)) * 8;
        int rb = wn + i * 16 + lr;
        boff[i] = rb * 32 + ((((rb >> 1) & 3) ^ segn)) * 8;
    }

    f32x4 acc1[4][4], acc3[4][4];
#pragma unroll
    for (int i = 0; i < 4; ++i)
#pragma unroll
        for (int j = 0; j < 4; ++j)
#pragma unroll
            for (int r = 0; r < 4; ++r) { acc1[i][j][r] = 0.f; acc3[i][j][r] = 0.f; }

    const bf16* B1base = B1w + ((size_t)e * FDIM + (size_t)nt * 128) * DDIM;
    const bf16* B3base = B3w + ((size_t)e * FDIM + (size_t)nt * 128) * DDIM;
    const int trow[2] = { tokbuf[srow], tokbuf[srow + 64] };

    for (int kk = 0; kk < DDIM; kk += 32) {
#pragma unroll
        for (int it = 0; it < 2; ++it) {
            int row = srow + it * 64;
            size_t col = kk + acol;
            async_copy16(xb + (size_t)trow[it] * DDIM + col, As + it * 2048 + ldsw);
            async_copy16(B1base + (size_t)row * DDIM + col, B1s + it * 2048 + ldsw);
            async_copy16(B3base + (size_t)row * DDIM + col, B3s + it * 2048 + ldsw);
        }
        __syncthreads();
        bf16x8 af[4], b1f[4], b3f[4];
#pragma unroll
        for (int i = 0; i < 4; ++i) {
            af[i] = *(const bf16x8*)(As + aoff[i]);
            b1f[i] = *(const bf16x8*)(B1s + boff[i]);
            b3f[i] = *(const bf16x8*)(B3s + boff[i]);
        }
#pragma unroll
        for (int i = 0; i < 4; ++i)
#pragma unroll
            for (int j = 0; j < 4; ++j) {
                acc1[i][j] = __builtin_amdgcn_mfma_f32_16x16x32_bf16(
                    af[i], b1f[j], acc1[i][j], 0, 0, 0);
                acc3[i][j] = __builtin_amdgcn_mfma_f32_16x16x32_bf16(
                    af[i], b3f[j], acc3[i][j], 0, 0, 0);
            }
        __syncthreads();
    }

    // C/D layout: col = lane&15, row = (lane>>4)*4 + reg
    const int lcol = lane & 15, lrow0 = (lane >> 4) * 4;
#pragma unroll
    for (int i = 0; i < 4; ++i) {
#pragma unroll
        for (int r = 0; r < 4; ++r) {
            int p = mt * 128 + wm + i * 16 + lrow0 + r;
            if (p >= count) continue;
            int slot = off + p;
            float wl = wlist[slot];
#pragma unroll
            for (int j = 0; j < 4; ++j) {
                int n = nt * 128 + wn + j * 16 + lcol;
                float a = acc1[i][j][r];
                float sv = a / (1.f + __expf(-a));
                Hbuf[(size_t)slot * FDIM + n] = (bf16)(sv * acc3[i][j][r] * wl);
            }
        }
    }
}

// ------ GEMM2: ObufS[kslice][slot] = H @ w2t (split-K=2, no atomics) ------
__global__ __launch_bounds__(256) void k_gemm2(
    const bf16* __restrict__ Hbuf, const bf16* __restrict__ B2w,
    float* __restrict__ ObufS,
    const int* __restrict__ cnt, const int* __restrict__ offs)
{
    const int kslice = blockIdx.z >> 3, e = blockIdx.z & 7;
    const int mt = blockIdx.y, nt = blockIdx.x;
    const int count = cnt[e];
    if (mt * 128 >= count) return;
    const int off = offs[e];
    const int tid = threadIdx.x;
    const int lane = tid & 63;
    const int wid = tid >> 6;
    const int wm = (wid >> 1) * 64, wn = (wid & 1) * 64;
    const int lr = lane & 15, segn = lane >> 4;

    __shared__ __attribute__((aligned(16))) bf16 As[128 * 32];
    __shared__ __attribute__((aligned(16))) bf16 Bs[128 * 32];

    const int srow = tid >> 2;
    const int gseg = (tid & 3) ^ ((srow >> 1) & 3);
    const int ldsw = wid * 512;
    const size_t acol = (size_t)gseg * 8;

    int aoff[4], boff[4];
#pragma unroll
    for (int i = 0; i < 4; ++i) {
        int ra = wm + i * 16 + lr;
        aoff[i] = ra * 32 + ((((ra >> 1) & 3) ^ segn)) * 8;
        int rb = wn + i * 16 + lr;
        boff[i] = rb * 32 + ((((rb >> 1) & 3) ^ segn)) * 8;
    }

    f32x4 acc[4][4];
#pragma unroll
    for (int i = 0; i < 4; ++i)
#pragma unroll
        for (int j = 0; j < 4; ++j)
#pragma unroll
            for (int r = 0; r < 4; ++r) acc[i][j][r] = 0.f;

    const bf16* Abase = Hbuf + (size_t)(off + mt * 128) * FDIM;  // HROWS slack covers tail
    const bf16* Bbase = B2w + ((size_t)e * DDIM + (size_t)nt * 128) * FDIM;
    const int k0 = kslice * (FDIM / 2), k1 = k0 + FDIM / 2;

    for (int kk = k0; kk < k1; kk += 32) {
#pragma unroll
        for (int it = 0; it < 2; ++it) {
            int row = srow + it * 64;
            size_t col = kk + acol;
            async_copy16(Abase + (size_t)row * FDIM + col, As + it * 2048 + ldsw);
            async_copy16(Bbase + (size_t)row * FDIM + col, Bs + it * 2048 + ldsw);
        }
        __syncthreads();
        bf16x8 af[4], bfr[4];
#pragma unroll
        for (int i = 0; i < 4; ++i) {
            af[i] = *(const bf16x8*)(As + aoff[i]);
            bfr[i] = *(const bf16x8*)(Bs + boff[i]);
        }
#pragma unroll
        for (int i = 0; i < 4; ++i)
#pragma unroll
            for (int j = 0; j < 4; ++j)
                acc[i][j] = __builtin_amdgcn_mfma_f32_16x16x32_bf16(
                    af[i], bfr[j], acc[i][j], 0, 0, 0);
        __syncthreads();
    }

    const int lcol = lane & 15, lrow0 = (lane >> 4) * 4;
    float* Oslice = ObufS + (size_t)kslice * NSLOT * DDIM;
#pragma unroll
    for (int i = 0; i < 4; ++i) {
#pragma unroll
        for (int r = 0; r < 4; ++r) {
            int p = mt * 128 + wm + i * 16 + lrow0 + r;
            if (p >= count) continue;
            float* orow = Oslice + (size_t)(off + p) * DDIM + nt * 128 + wn + lcol;
#pragma unroll
            for (int j = 0; j < 4; ++j) orow[j * 16] = acc[i][j][r];
        }
    }
}

// ------ combine: out[t] = sum over 2 slots x 2 kslices --------------------
__global__ __launch_bounds__(256) void k_combine(
    const float* __restrict__ ObufS, const int* __restrict__ inv,
    float* __restrict__ out)
{
    int i = blockIdx.x * 256 + threadIdx.x;   // T*D/4 float4 units
    int t = i >> 8, d4 = i & 255;             // D/4 = 256
    int s0 = inv[2 * t], s1 = inv[2 * t + 1];
    const float4* O = (const float4*)ObufS;
    float4 a = O[(size_t)s0 * 256 + d4];
    float4 b = O[(size_t)s1 * 256 + d4];
    float4 c = O[(size_t)(NSLOT + s0) * 256 + d4];
    float4 d = O[(size_t)(NSLOT + s1) * 256 + d4];
    float4 r;
    r.x = a.x + b.x + c.x + d.x;
    r.y = a.y + b.y + c.y + d.y;
    r.z = a.z + b.z + c.z + d.z;
    r.w = a.w + b.w + c.w + d.w;
    ((float4*)out)[i] = r;
}

extern "C" void kernel_launch(void* const* d_in, const int* in_sizes, int n_in,
                              void* d_out, int out_size, void* d_ws, size_t ws_size,
                              hipStream_t stream)
{
    const float* x  = (const float*)d_in[0];
    const float* gw = (const float*)d_in[1];
    const float* w1 = (const float*)d_in[2];
    const float* w3 = (const float*)d_in[3];
    const float* w2 = (const float*)d_in[4];
    float* out = (float*)d_out;

    char* ws = (char*)d_ws;
    size_t o = 0;
    auto alloc = [&](size_t bytes) {
        char* p = ws + o;
        o += (bytes + 255) & ~(size_t)255;
        return p;
    };
    const size_t wsz = (size_t)NEXP * DDIM * FDIM * sizeof(bf16);   // 64 MiB
    bf16*  w1t   = (bf16*)alloc(wsz);                        // later: w2t
    bf16*  w3t   = (bf16*)alloc(wsz);                        // later: ObufS (fp32, exactly 64 MiB)
    bf16*  Hbuf  = (bf16*)alloc((size_t)HROWS * FDIM * sizeof(bf16));
    bf16*  xb    = (bf16*)alloc((size_t)T_TOK * DDIM * sizeof(bf16));
    int*   topE  = (int*)alloc(T_TOK * 2 * sizeof(int));
    float* topW  = (float*)alloc(T_TOK * 2 * sizeof(float));
    int*   cnt   = (int*)alloc(NEXP * sizeof(int));
    int*   offs  = (int*)alloc(NEXP * sizeof(int));
    int*   fill  = (int*)alloc(NEXP * sizeof(int));
    int*   list  = (int*)alloc(NSLOT * sizeof(int));
    float* wlist = (float*)alloc(NSLOT * sizeof(float));
    int*   inv   = (int*)alloc(NSLOT * sizeof(int));
    bf16*  w2t   = w1t;                   // after gemm01, w1t region is free
    float* ObufS = (float*)w3t;           // after gemm01, w3t region is free (2*NSLOT*DDIM*4 = 64 MiB)

    hipMemsetAsync(out, 0, (size_t)out_size * sizeof(float), stream);
    hipMemsetAsync(cnt, 0, NEXP * sizeof(int), stream);

    float* out_rl = out + (size_t)T_TOK * DDIM;

    k_cast<<<T_TOK * DDIM / 4 / 256, 256, 0, stream>>>(x, xb, T_TOK * DDIM / 4);
    k_router<<<T_TOK / 4, 256, 0, stream>>>(x, gw, out_rl, topE, topW, cnt);
    k_scan<<<1, 64, 0, stream>>>(cnt, offs, fill);
    k_build<<<(T_TOK + 255) / 256, 256, 0, stream>>>(topE, topW, offs, fill, list, wlist, inv);

    k_tc64<<<dim3(FDIM / 64, DDIM / 64, NEXP), 256, 0, stream>>>(w1, w1t, DDIM, FDIM);
    k_tc64<<<dim3(FDIM / 64, DDIM / 64, NEXP), 256, 0, stream>>>(w3, w3t, DDIM, FDIM);

    k_gemm01<<<dim3(FDIM / 128, T_TOK / 128, NEXP), 256, 0, stream>>>(
        xb, w1t, w3t, Hbuf, cnt, offs, list, wlist);

    k_tc64<<<dim3(DDIM / 64, FDIM / 64, NEXP), 256, 0, stream>>>(w2, w2t, FDIM, DDIM);

    k_gemm2<<<dim3(DDIM / 128, T_TOK / 128, NEXP * 2), 256, 0, stream>>>(
        Hbuf, w2t, ObufS, cnt, offs);

    k_combine<<<T_TOK * DDIM / 4 / 256, 256, 0, stream>>>(ObufS, inv, out);
}